// Round 9
// baseline (430.977 us; speedup 1.0000x reference)
//
#include <hip/hip_runtime.h>
#include <hip/hip_bf16.h>
#include <stdint.h>

// MoE: E=8 experts, M=4096 tokens, K=2048 hidden, I=1408 intermediate, TOPK=2
#define EXPERTS 8
#define MTOK 4096
#define KDIM 2048
#define IDIM 1408
#define NDIM 2816   // 2*I
#define CAP  8192   // per-expert bucket capacity (worst case)

typedef __attribute__((ext_vector_type(8))) short bf16x8;
typedef __attribute__((ext_vector_type(4))) float f32x4;

__device__ __forceinline__ unsigned short f2bf(float x) {
    unsigned u = __float_as_uint(x);
    u = u + 0x7fffu + ((u >> 16) & 1u);   // RNE
    return (unsigned short)(u >> 16);
}

__device__ __forceinline__ void gload16(const void* g, void* l) {
    __builtin_amdgcn_global_load_lds(
        (const __attribute__((address_space(1))) void*)g,
        (__attribute__((address_space(3))) void*)l, 16, 0, 0);
}

// ---------------- fp32 -> bf16 conversion (vectorized) ----------------
__global__ void __launch_bounds__(256) conv_bf16(const float* __restrict__ src,
                                                 unsigned short* __restrict__ dst, int n4) {
    int i = blockIdx.x * 256 + threadIdx.x;
    int st = gridDim.x * 256;
    for (; i < n4; i += st) {
        float4 v = reinterpret_cast<const float4*>(src)[i];
        ushort4 r;
        r.x = f2bf(v.x); r.y = f2bf(v.y); r.z = f2bf(v.z); r.w = f2bf(v.w);
        reinterpret_cast<ushort4*>(dst)[i] = r;
    }
}

// ---------------- router ----------------
__global__ void __launch_bounds__(256) router(const float* __restrict__ tw,
                                              const int* __restrict__ ids,
                                              int* __restrict__ tok, float* __restrict__ wgt,
                                              int* __restrict__ cnt) {
    int m = blockIdx.x * 256 + threadIdx.x;
    if (m >= MTOK) return;
#pragma unroll
    for (int t = 0; t < 2; t++) {
        int e = ids[m * 2 + t];
        int slot = atomicAdd(&cnt[e], 1);
        tok[e * CAP + slot] = m;
        wgt[e * CAP + slot] = tw[m * 2 + t];
    }
}

__global__ void scan_off(const int* __restrict__ cnt, int* __restrict__ off) {
    if (threadIdx.x == 0) {
        int s = 0;
        for (int e = 0; e < EXPERTS; e++) { off[e] = s; s += cnt[e]; }
    }
}

// ====================================================================
// BM=256 x BN=64 tiles, BK=32, 256 thr (4 waves stacked in M), single
// LDS buffer (A 16KB @ 0, B 4KB @ 16384), round-4 2-barrier schedule.
// Rationale: L3->L2 fabric BW is the binding constraint; B-panel traffic
// scales as 1/BM, so BM 128->256 halves it. Expert->XCD pinning kept.
// Swizzle (round-4 verified): 16B slot phys = g ^ ((row>>1)&3), applied
// via inverse-permuted global source + matching ds_read offset.
// ====================================================================

// ---------------- GEMM1 + SiLU*up -> act (bf16) ----------------
__global__ void __launch_bounds__(256) gemm1_silu(
    const unsigned short* __restrict__ hsb,
    const unsigned short* __restrict__ w1b,
    const int* __restrict__ tok,
    const int* __restrict__ cnt,
    const int* __restrict__ off,
    unsigned short* __restrict__ act) {
    const int bid = blockIdx.x;
    const int e = bid & 7;       // XCD pin: bid%8 -> XCD
    const int j = bid >> 3;
    const int rb = j / 44;       // rb-major: co-resident blocks share A-tile
    const int cb = j - rb * 44;  // 0..43 (44 * 32 = 1408 I-cols)
    const int cnt_e = cnt[e];
    if (rb * 256 >= cnt_e) return;
    const int off_e = off[e];
    const int NT = KDIM / 32;    // 64

    __shared__ __align__(16) char smem[20480];   // A 16KB + B 4KB
    __shared__ int toks[256];

    const int tid = threadIdx.x;
    const int w = tid >> 6, lane = tid & 63;
    {
        int slot = rb * 256 + tid;
        toks[tid] = (slot < cnt_e) ? tok[e * CAP + slot] : 0;
    }
    __syncthreads();

    // ---- staging: A 1024 chunks (4/thread), B 256 chunks (1/thread)
    // chunk c: row = c>>2, phys slot p = c&3, logical g = p ^ ((row>>1)&3)
    size_t sA[4]; int dA[4];
#pragma unroll
    for (int k = 0; k < 4; k++) {
        int c = k * 256 + tid;
        int row = c >> 2, g = (c & 3) ^ ((row >> 1) & 3);
        sA[k] = (size_t)toks[row] * KDIM + g * 8;
        dA[k] = c * 16;
    }
    const size_t w1base = (size_t)e * NDIM * KDIM;
    size_t sB0; int dB0;
    {
        int c = tid;              // 256 chunks: 64 rows x 4 slots
        int row = c >> 2, g = (c & 3) ^ ((row >> 1) & 3);
        int G = row >> 4;         // 0..3; even = gate, odd = up (16-col slices)
        int wrow = ((G & 1) ? IDIM : 0) + cb * 32 + (G >> 1) * 16 + (row & 15);
        sB0 = w1base + (size_t)wrow * KDIM + g * 8;
        dB0 = 16384 + c * 16;
    }

    const int l16 = lane & 15, lg = lane >> 4;
    int aoff[4], boff[4];
#pragma unroll
    for (int m = 0; m < 4; m++) {
        int r = w * 64 + m * 16 + l16;          // waves stacked in M
        aoff[m] = r * 64 + ((lg ^ ((r >> 1) & 3)) * 16);
    }
#pragma unroll
    for (int n = 0; n < 4; n++) {
        int r = n * 16 + l16;                   // B rows 0..63
        boff[n] = 16384 + r * 64 + ((lg ^ ((r >> 1) & 3)) * 16);
    }

    f32x4 acc[4][4];
#pragma unroll
    for (int m = 0; m < 4; m++)
#pragma unroll
        for (int n = 0; n < 4; n++) acc[m][n] = {0.f, 0.f, 0.f, 0.f};

    for (int kt = 0; kt < NT; ++kt) {
        const int kof = kt * 32;
#pragma unroll
        for (int k = 0; k < 4; k++) gload16(hsb + sA[k] + kof, smem + dA[k]);
        gload16(w1b + sB0 + kof, smem + dB0);
        __syncthreads();

        bf16x8 af[4], bf[4];
#pragma unroll
        for (int m = 0; m < 4; m++) af[m] = *(const bf16x8*)(smem + aoff[m]);
#pragma unroll
        for (int n = 0; n < 4; n++) bf[n] = *(const bf16x8*)(smem + boff[n]);
#pragma unroll
        for (int m = 0; m < 4; m++)
#pragma unroll
            for (int n = 0; n < 4; n++)
                acc[m][n] = __builtin_amdgcn_mfma_f32_16x16x32_bf16(af[m], bf[n], acc[m][n], 0, 0, 0);
        __syncthreads();
    }

    // epilogue: frag pairs (0,1),(2,3) are (gate,up) on same 16 cols
#pragma unroll
    for (int m = 0; m < 4; m++) {
#pragma unroll
        for (int np = 0; np < 2; np++) {
            f32x4 g4 = acc[m][np * 2];
            f32x4 u4 = acc[m][np * 2 + 1];
            int icol = cb * 32 + np * 16 + l16;
#pragma unroll
            for (int j2 = 0; j2 < 4; j2++) {
                int grow = rb * 256 + w * 64 + m * 16 + lg * 4 + j2;
                if (grow < cnt_e) {
                    float gt = g4[j2], up = u4[j2];
                    float s = gt / (1.f + __expf(-gt));
                    act[(size_t)(off_e + grow) * IDIM + icol] = f2bf(s * up);
                }
            }
        }
    }
}

// ---------------- GEMM2 + weighted scatter ----------------
__global__ void __launch_bounds__(256) gemm2_scatter(
    const unsigned short* __restrict__ act,
    const unsigned short* __restrict__ w2b,
    const int* __restrict__ tok,
    const float* __restrict__ wgt,
    const int* __restrict__ cnt,
    const int* __restrict__ off,
    float* __restrict__ out) {
    const int bid = blockIdx.x;
    const int e = bid & 7;       // XCD pin
    const int j = bid >> 3;
    const int rb = j >> 5;       // rb-major
    const int cb = j & 31;       // 0..31 (32*64 = 2048 out cols)
    const int cnt_e = cnt[e];
    if (rb * 256 >= cnt_e) return;
    const int off_e = off[e];
    const int NT = IDIM / 32;    // 44

    __shared__ __align__(16) char smem[20480];
    __shared__ int toks[256];
    __shared__ float wgts[256];

    const int tid = threadIdx.x;
    const int w = tid >> 6, lane = tid & 63;
    {
        int slot = rb * 256 + tid;
        bool v = slot < cnt_e;
        toks[tid] = v ? tok[e * CAP + slot] : 0;
        wgts[tid] = v ? wgt[e * CAP + slot] : 0.f;
    }
    __syncthreads();

    size_t sA[4]; int dA[4];
#pragma unroll
    for (int k = 0; k < 4; k++) {
        int c = k * 256 + tid;
        int row = c >> 2, g = (c & 3) ^ ((row >> 1) & 3);
        int s = rb * 256 + row;
        sA[k] = (size_t)(off_e + (s < cnt_e ? s : 0)) * IDIM + g * 8;
        dA[k] = c * 16;
    }
    const size_t w2base = (size_t)e * KDIM * IDIM;
    size_t sB0; int dB0;
    {
        int c = tid;
        int row = c >> 2, g = (c & 3) ^ ((row >> 1) & 3);
        sB0 = w2base + (size_t)(cb * 64 + row) * IDIM + g * 8;
        dB0 = 16384 + c * 16;
    }

    const int l16 = lane & 15, lg = lane >> 4;
    int aoff[4], boff[4];
#pragma unroll
    for (int m = 0; m < 4; m++) {
        int r = w * 64 + m * 16 + l16;
        aoff[m] = r * 64 + ((lg ^ ((r >> 1) & 3)) * 16);
    }
#pragma unroll
    for (int n = 0; n < 4; n++) {
        int r = n * 16 + l16;
        boff[n] = 16384 + r * 64 + ((lg ^ ((r >> 1) & 3)) * 16);
    }

    f32x4 acc[4][4];
#pragma unroll
    for (int m = 0; m < 4; m++)
#pragma unroll
        for (int n = 0; n < 4; n++) acc[m][n] = {0.f, 0.f, 0.f, 0.f};

    for (int kt = 0; kt < NT; ++kt) {
        const int kof = kt * 32;
#pragma unroll
        for (int k = 0; k < 4; k++) gload16(act + sA[k] + kof, smem + dA[k]);
        gload16(w2b + sB0 + kof, smem + dB0);
        __syncthreads();

        bf16x8 af[4], bf[4];
#pragma unroll
        for (int m = 0; m < 4; m++) af[m] = *(const bf16x8*)(smem + aoff[m]);
#pragma unroll
        for (int n = 0; n < 4; n++) bf[n] = *(const bf16x8*)(smem + boff[n]);
#pragma unroll
        for (int m = 0; m < 4; m++)
#pragma unroll
            for (int n = 0; n < 4; n++)
                acc[m][n] = __builtin_amdgcn_mfma_f32_16x16x32_bf16(af[m], bf[n], acc[m][n], 0, 0, 0);
        __syncthreads();
    }

    // scatter: out[token, k] += weight * y  (TOPK=2, fp32 atomic add, commutative)
#pragma unroll
    for (int m = 0; m < 4; m++) {
#pragma unroll
        for (int n = 0; n < 4; n++) {
            int kcol = cb * 64 + n * 16 + l16;
#pragma unroll
            for (int j2 = 0; j2 < 4; j2++) {
                int lrow = w * 64 + m * 16 + lg * 4 + j2;
                if (rb * 256 + lrow < cnt_e) {
                    atomicAdd(&out[(size_t)toks[lrow] * KDIM + kcol],
                              wgts[lrow] * acc[m][n][j2]);
                }
            }
        }
    }
}

extern "C" void kernel_launch(void* const* d_in, const int* in_sizes, int n_in,
                              void* d_out, int out_size, void* d_ws, size_t ws_size,
                              hipStream_t stream) {
    const float* hs  = (const float*)d_in[0];
    const float* w1  = (const float*)d_in[1];
    const float* w2  = (const float*)d_in[2];
    const float* tw  = (const float*)d_in[3];
    const int*   ids = (const int*)d_in[4];
    float* out = (float*)d_out;

    char* ws = (char*)d_ws;
    unsigned short* w1b  = (unsigned short*)(ws);                  //  92,274,688
    unsigned short* w2b  = (unsigned short*)(ws + 92274688ull);    //  46,137,344
    unsigned short* hsb  = (unsigned short*)(ws + 138412032ull);   //  16,777,216
    unsigned short* actb = (unsigned short*)(ws + 155189248ull);   //  23,068,672
    int*   tokb = (int*)  (ws + 178257920ull);
    float* wgtb = (float*)(ws + 178520064ull);
    int*   cntb = (int*)  (ws + 178782208ull);
    int*   offb = (int*)  (ws + 178782240ull);

    hipMemsetAsync(d_out, 0, (size_t)MTOK * KDIM * sizeof(float), stream);
    hipMemsetAsync(cntb, 0, 64, stream);

    conv_bf16<<<4096, 256, 0, stream>>>(w1, w1b, EXPERTS * NDIM * KDIM / 4);
    conv_bf16<<<2048, 256, 0, stream>>>(w2, w2b, EXPERTS * KDIM * IDIM / 4);
    conv_bf16<<<1024, 256, 0, stream>>>(hs, hsb, MTOK * KDIM / 4);

    router<<<MTOK / 256, 256, 0, stream>>>(tw, ids, tokb, wgtb, cntb);
    scan_off<<<1, 64, 0, stream>>>(cntb, offb);

    // linear grids with bid%8 == expert  (expert->XCD pinning)
    gemm1_silu<<<dim3(44 * 32 * 8, 1, 1), 256, 0, stream>>>(hsb, w1b, tokb, cntb, offb, actb);
    gemm2_scatter<<<dim3(32 * 32 * 8, 1, 1), 256, 0, stream>>>(actb, w2b, tokb, wgtb, cntb, offb, out);
}

// Round 10
// 411.207 us; speedup vs baseline: 1.0481x; 1.0481x over previous
//
#include <hip/hip_runtime.h>
#include <hip/hip_bf16.h>
#include <stdint.h>

// MoE: E=8 experts, M=4096 tokens, K=2048 hidden, I=1408 intermediate, TOPK=2
#define EXPERTS 8
#define MTOK 4096
#define KDIM 2048
#define IDIM 1408
#define NDIM 2816   // 2*I
#define CAP  8192   // per-expert bucket capacity (worst case)

typedef __attribute__((ext_vector_type(8))) short bf16x8;
typedef __attribute__((ext_vector_type(4))) float f32x4;

__device__ __forceinline__ unsigned short f2bf(float x) {
    unsigned u = __float_as_uint(x);
    u = u + 0x7fffu + ((u >> 16) & 1u);   // RNE
    return (unsigned short)(u >> 16);
}

__device__ __forceinline__ void gload16(const void* g, void* l) {
    __builtin_amdgcn_global_load_lds(
        (const __attribute__((address_space(1))) void*)g,
        (__attribute__((address_space(3))) void*)l, 16, 0, 0);
}

// ---------------- fp32 -> bf16 conversion (vectorized) ----------------
__global__ void __launch_bounds__(256) conv_bf16(const float* __restrict__ src,
                                                 unsigned short* __restrict__ dst, int n4) {
    int i = blockIdx.x * 256 + threadIdx.x;
    int st = gridDim.x * 256;
    for (; i < n4; i += st) {
        float4 v = reinterpret_cast<const float4*>(src)[i];
        ushort4 r;
        r.x = f2bf(v.x); r.y = f2bf(v.y); r.z = f2bf(v.z); r.w = f2bf(v.w);
        reinterpret_cast<ushort4*>(dst)[i] = r;
    }
}

// ---------------- router ----------------
__global__ void __launch_bounds__(256) router(const float* __restrict__ tw,
                                              const int* __restrict__ ids,
                                              int* __restrict__ tok, float* __restrict__ wgt,
                                              int* __restrict__ cnt) {
    int m = blockIdx.x * 256 + threadIdx.x;
    if (m >= MTOK) return;
#pragma unroll
    for (int t = 0; t < 2; t++) {
        int e = ids[m * 2 + t];
        int slot = atomicAdd(&cnt[e], 1);
        tok[e * CAP + slot] = m;
        wgt[e * CAP + slot] = tw[m * 2 + t];
    }
}

__global__ void scan_off(const int* __restrict__ cnt, int* __restrict__ off) {
    if (threadIdx.x == 0) {
        int s = 0;
        for (int e = 0; e < EXPERTS; e++) { off[e] = s; s += cnt[e]; }
    }
}

// ====================================================================
// Round-8 ring GEMMs (128x128, BK=32, 3-slot 16KB ring, counted vmcnt(4))
// + expert->XCD pinning + *cb-major* block order: rb = j % 64 (fastest),
// cb = j / 64. Co-resident blocks on an XCD now share the SAME B panel
// (256KB, L2-hit for 7 of 8 rb-siblings) instead of streaming 22
// different panels (5.6MB, L2-thrash -> L3 latency every K-step).
// Ring's ~2-iteration prefetch cover (~600cy) then fully hides ~200cy
// L2-hit latency. Swizzle unchanged (round-4 verified).
// ====================================================================

// ---------------- GEMM1 + SiLU*up -> act (bf16) ----------------
__global__ void __launch_bounds__(256, 3) gemm1_silu(
    const unsigned short* __restrict__ hsb,
    const unsigned short* __restrict__ w1b,
    const int* __restrict__ tok,
    const int* __restrict__ cnt,
    const int* __restrict__ off,
    unsigned short* __restrict__ act) {
    const int bid = blockIdx.x;
    const int e = bid & 7;       // XCD pin: bid%8 -> XCD
    const int j = bid >> 3;      // 0..1407
    const int rb = j & 63;       // cb-major: rb fastest -> co-resident share B panel
    const int cb = j >> 6;       // 0..21 (22*64 = 1408 gate cols)
    const int cnt_e = cnt[e];
    if (rb * 128 >= cnt_e) return;
    const int off_e = off[e];
    const int NT = KDIM / 32;    // 64

    __shared__ __align__(16) char smem[49152];   // 3 x 16KB ring
    __shared__ int toks[128];

    const int tid = threadIdx.x;
    const int w = tid >> 6, lane = tid & 63;
    if (tid < 128) {
        int slot = rb * 128 + tid;
        toks[tid] = (slot < cnt_e) ? tok[e * CAP + slot] : 0;
    }
    __syncthreads();

    // staging geometry (round-4 verified): per-slot layout A@0(8KB), B@8192(8KB)
    const int o0 = w * 1024 + lane * 16;
    const int row0 = o0 >> 6, g0 = ((o0 >> 4) & 3) ^ ((row0 >> 1) & 3);
    const int o1 = 4096 + o0;
    const int row1 = o1 >> 6, g1 = ((o1 >> 4) & 3) ^ ((row1 >> 1) & 3);

    const int G0 = row0 >> 4, G1 = row1 >> 4;
    const size_t w1base = (size_t)e * NDIM * KDIM;
    const int wrow0 = ((G0 & 1) ? IDIM : 0) + cb * 64 + (G0 >> 1) * 16 + (row0 & 15);
    const int wrow1 = ((G1 & 1) ? IDIM : 0) + cb * 64 + (G1 >> 1) * 16 + (row1 & 15);

    const size_t srcA0 = (size_t)toks[row0] * KDIM + g0 * 8;
    const size_t srcA1 = (size_t)toks[row1] * KDIM + g1 * 8;
    const size_t srcB0 = w1base + (size_t)wrow0 * KDIM + g0 * 8;
    const size_t srcB1 = w1base + (size_t)wrow1 * KDIM + g1 * 8;

    const int wr = w >> 1, wc = w & 1;
    const int l16 = lane & 15, lg = lane >> 4;
    int aoff[4], boff[4];
#pragma unroll
    for (int m = 0; m < 4; m++) {
        int r = wr * 64 + m * 16 + l16;
        aoff[m] = r * 64 + ((lg ^ ((r >> 1) & 3)) * 16);
    }
#pragma unroll
    for (int n = 0; n < 4; n++) {
        int r = wc * 64 + n * 16 + l16;
        boff[n] = 8192 + r * 64 + ((lg ^ ((r >> 1) & 3)) * 16);
    }

    f32x4 acc[4][4];
#pragma unroll
    for (int m = 0; m < 4; m++)
#pragma unroll
        for (int n = 0; n < 4; n++) acc[m][n] = {0.f, 0.f, 0.f, 0.f};

#define STG1(t, base) { const int kof_ = (t) * 32; char* b_ = smem + (base); \
    gload16(hsb + srcA0 + kof_, b_ + w * 1024); \
    gload16(hsb + srcA1 + kof_, b_ + 4096 + w * 1024); \
    gload16(w1b + srcB0 + kof_, b_ + 8192 + w * 1024); \
    gload16(w1b + srcB1 + kof_, b_ + 12288 + w * 1024); }

    // prologue: stage tiles 0,1 into slots 0,1; wait tile 0 only
    STG1(0, 0); STG1(1, 16384);
    asm volatile("s_waitcnt vmcnt(4)" ::: "memory");
    __builtin_amdgcn_sched_barrier(0);
    __builtin_amdgcn_s_barrier();

    int sl_t = 0;        // slot byte base of tile t
    int sl_p = 32768;    // slot byte base of tile t+2

#pragma unroll 1
    for (int t = 0; t < NT; ++t) {
        if (t + 2 < NT) STG1(t + 2, sl_p);
        __builtin_amdgcn_sched_barrier(0);

        const char* db = smem + sl_t;
        bf16x8 af[4], bf[4];
#pragma unroll
        for (int m = 0; m < 4; m++) af[m] = *(const bf16x8*)(db + aoff[m]);
#pragma unroll
        for (int n = 0; n < 4; n++) bf[n] = *(const bf16x8*)(db + boff[n]);
        __builtin_amdgcn_s_setprio(1);
#pragma unroll
        for (int m = 0; m < 4; m++)
#pragma unroll
            for (int n = 0; n < 4; n++)
                acc[m][n] = __builtin_amdgcn_mfma_f32_16x16x32_bf16(af[m], bf[n], acc[m][n], 0, 0, 0);
        __builtin_amdgcn_s_setprio(0);
        __builtin_amdgcn_sched_barrier(0);
        if (t + 2 < NT)      { asm volatile("s_waitcnt vmcnt(4)" ::: "memory"); }
        else if (t + 1 < NT) { asm volatile("s_waitcnt vmcnt(0)" ::: "memory"); }
        __builtin_amdgcn_sched_barrier(0);
        __builtin_amdgcn_s_barrier();

        sl_t += 16384; if (sl_t == 49152) sl_t = 0;
        sl_p += 16384; if (sl_p == 49152) sl_p = 0;
    }
#undef STG1

    // epilogue: n even = gate frag, n+1 = up frag (same 16 cols)
#pragma unroll
    for (int m = 0; m < 4; m++) {
#pragma unroll
        for (int np = 0; np < 2; np++) {
            f32x4 g4 = acc[m][np * 2];
            f32x4 u4 = acc[m][np * 2 + 1];
            int icol = cb * 64 + (wc * 2 + np) * 16 + l16;
#pragma unroll
            for (int j2 = 0; j2 < 4; j2++) {
                int grow = rb * 128 + wr * 64 + m * 16 + lg * 4 + j2;
                if (grow < cnt_e) {
                    float gt = g4[j2], up = u4[j2];
                    float s = gt / (1.f + __expf(-gt));
                    act[(size_t)(off_e + grow) * IDIM + icol] = f2bf(s * up);
                }
            }
        }
    }
}

// ---------------- GEMM2 + weighted scatter ----------------
__global__ void __launch_bounds__(256, 3) gemm2_scatter(
    const unsigned short* __restrict__ act,
    const unsigned short* __restrict__ w2b,
    const int* __restrict__ tok,
    const float* __restrict__ wgt,
    const int* __restrict__ cnt,
    const int* __restrict__ off,
    float* __restrict__ out) {
    const int bid = blockIdx.x;
    const int e = bid & 7;       // XCD pin
    const int j = bid >> 3;      // 0..1023
    const int rb = j & 63;       // cb-major: rb fastest
    const int cb = j >> 6;       // 0..15 (16*128 = 2048 out cols)
    const int cnt_e = cnt[e];
    if (rb * 128 >= cnt_e) return;
    const int off_e = off[e];
    const int NT = IDIM / 32;    // 44

    __shared__ __align__(16) char smem[49152];
    __shared__ int toks[128];
    __shared__ float wgts[128];

    const int tid = threadIdx.x;
    const int w = tid >> 6, lane = tid & 63;
    if (tid < 128) {
        int slot = rb * 128 + tid;
        bool v = slot < cnt_e;
        toks[tid] = v ? tok[e * CAP + slot] : 0;
        wgts[tid] = v ? wgt[e * CAP + slot] : 0.f;
    }
    __syncthreads();

    const int o0 = w * 1024 + lane * 16;
    const int row0 = o0 >> 6, g0 = ((o0 >> 4) & 3) ^ ((row0 >> 1) & 3);
    const int o1 = 4096 + o0;
    const int row1 = o1 >> 6, g1 = ((o1 >> 4) & 3) ^ ((row1 >> 1) & 3);

    const int s0 = rb * 128 + row0, s1 = rb * 128 + row1;
    const size_t pa0 = (size_t)(off_e + (s0 < cnt_e ? s0 : 0)) * IDIM + g0 * 8;
    const size_t pa1 = (size_t)(off_e + (s1 < cnt_e ? s1 : 0)) * IDIM + g1 * 8;
    const size_t w2base = (size_t)e * KDIM * IDIM;
    const size_t pb0 = w2base + (size_t)(cb * 128 + row0) * IDIM + g0 * 8;
    const size_t pb1 = w2base + (size_t)(cb * 128 + row1) * IDIM + g1 * 8;

    const int wr = w >> 1, wc = w & 1;
    const int l16 = lane & 15, lg = lane >> 4;
    int aoff[4], boff[4];
#pragma unroll
    for (int m = 0; m < 4; m++) {
        int r = wr * 64 + m * 16 + l16;
        aoff[m] = r * 64 + ((lg ^ ((r >> 1) & 3)) * 16);
    }
#pragma unroll
    for (int n = 0; n < 4; n++) {
        int r = wc * 64 + n * 16 + l16;
        boff[n] = 8192 + r * 64 + ((lg ^ ((r >> 1) & 3)) * 16);
    }

    f32x4 acc[4][4];
#pragma unroll
    for (int m = 0; m < 4; m++)
#pragma unroll
        for (int n = 0; n < 4; n++) acc[m][n] = {0.f, 0.f, 0.f, 0.f};

#define STG2(t, base) { const int kof_ = (t) * 32; char* b_ = smem + (base); \
    gload16(act + pa0 + kof_, b_ + w * 1024); \
    gload16(act + pa1 + kof_, b_ + 4096 + w * 1024); \
    gload16(w2b + pb0 + kof_, b_ + 8192 + w * 1024); \
    gload16(w2b + pb1 + kof_, b_ + 12288 + w * 1024); }

    STG2(0, 0); STG2(1, 16384);
    asm volatile("s_waitcnt vmcnt(4)" ::: "memory");
    __builtin_amdgcn_sched_barrier(0);
    __builtin_amdgcn_s_barrier();

    int sl_t = 0;
    int sl_p = 32768;

#pragma unroll 1
    for (int t = 0; t < NT; ++t) {
        if (t + 2 < NT) STG2(t + 2, sl_p);
        __builtin_amdgcn_sched_barrier(0);

        const char* db = smem + sl_t;
        bf16x8 af[4], bf[4];
#pragma unroll
        for (int m = 0; m < 4; m++) af[m] = *(const bf16x8*)(db + aoff[m]);
#pragma unroll
        for (int n = 0; n < 4; n++) bf[n] = *(const bf16x8*)(db + boff[n]);
        __builtin_amdgcn_s_setprio(1);
#pragma unroll
        for (int m = 0; m < 4; m++)
#pragma unroll
            for (int n = 0; n < 4; n++)
                acc[m][n] = __builtin_amdgcn_mfma_f32_16x16x32_bf16(af[m], bf[n], acc[m][n], 0, 0, 0);
        __builtin_amdgcn_s_setprio(0);
        __builtin_amdgcn_sched_barrier(0);
        if (t + 2 < NT)      { asm volatile("s_waitcnt vmcnt(4)" ::: "memory"); }
        else if (t + 1 < NT) { asm volatile("s_waitcnt vmcnt(0)" ::: "memory"); }
        __builtin_amdgcn_sched_barrier(0);
        __builtin_amdgcn_s_barrier();

        sl_t += 16384; if (sl_t == 49152) sl_t = 0;
        sl_p += 16384; if (sl_p == 49152) sl_p = 0;
    }
#undef STG2

    // scatter: out[token, k] += weight * y  (TOPK=2, fp32 atomic add, commutative)
#pragma unroll
    for (int m = 0; m < 4; m++) {
#pragma unroll
        for (int n = 0; n < 4; n++) {
            int kcol = cb * 128 + wc * 64 + n * 16 + l16;
#pragma unroll
            for (int j2 = 0; j2 < 4; j2++) {
                int lrow = wr * 64 + m * 16 + lg * 4 + j2;
                if (rb * 128 + lrow < cnt_e) {
                    atomicAdd(&out[(size_t)toks[lrow] * KDIM + kcol],
                              wgts[lrow] * acc[m][n][j2]);
                }
            }
        }
    }
}

extern "C" void kernel_launch(void* const* d_in, const int* in_sizes, int n_in,
                              void* d_out, int out_size, void* d_ws, size_t ws_size,
                              hipStream_t stream) {
    const float* hs  = (const float*)d_in[0];
    const float* w1  = (const float*)d_in[1];
    const float* w2  = (const float*)d_in[2];
    const float* tw  = (const float*)d_in[3];
    const int*   ids = (const int*)d_in[4];
    float* out = (float*)d_out;

    char* ws = (char*)d_ws;
    unsigned short* w1b  = (unsigned short*)(ws);                  //  92,274,688
    unsigned short* w2b  = (unsigned short*)(ws + 92274688ull);    //  46,137,344
    unsigned short* hsb  = (unsigned short*)(ws + 138412032ull);   //  16,777,216
    unsigned short* actb = (unsigned short*)(ws + 155189248ull);   //  23,068,672
    int*   tokb = (int*)  (ws + 178257920ull);
    float* wgtb = (float*)(ws + 178520064ull);
    int*   cntb = (int*)  (ws + 178782208ull);
    int*   offb = (int*)  (ws + 178782240ull);

    hipMemsetAsync(d_out, 0, (size_t)MTOK * KDIM * sizeof(float), stream);
    hipMemsetAsync(cntb, 0, 64, stream);

    conv_bf16<<<4096, 256, 0, stream>>>(w1, w1b, EXPERTS * NDIM * KDIM / 4);
    conv_bf16<<<2048, 256, 0, stream>>>(w2, w2b, EXPERTS * KDIM * IDIM / 4);
    conv_bf16<<<1024, 256, 0, stream>>>(hs, hsb, MTOK * KDIM / 4);

    router<<<MTOK / 256, 256, 0, stream>>>(tw, ids, tokb, wgtb, cntb);
    scan_off<<<1, 64, 0, stream>>>(cntb, offb);

    // linear grids with bid%8 == expert  (expert->XCD pinning), cb-major order
    gemm1_silu<<<dim3(22 * 64 * 8, 1, 1), 256, 0, stream>>>(hsb, w1b, tokb, cntb, offb, actb);
    gemm2_scatter<<<dim3(16 * 64 * 8, 1, 1), 256, 0, stream>>>(actb, w2b, tokb, wgtb, cntb, offb, out);
}

// Round 11
// 395.229 us; speedup vs baseline: 1.0904x; 1.0404x over previous
//
#include <hip/hip_runtime.h>
#include <hip/hip_bf16.h>
#include <stdint.h>

// MoE: E=8 experts, M=4096 tokens, K=2048 hidden, I=1408 intermediate, TOPK=2
#define EXPERTS 8
#define MTOK 4096
#define KDIM 2048
#define IDIM 1408
#define NDIM 2816   // 2*I
#define CAP  8192   // per-expert bucket capacity (worst case)

typedef __attribute__((ext_vector_type(8))) short bf16x8;
typedef __attribute__((ext_vector_type(4))) float f32x4;

__device__ __forceinline__ unsigned short f2bf(float x) {
    unsigned u = __float_as_uint(x);
    u = u + 0x7fffu + ((u >> 16) & 1u);   // RNE
    return (unsigned short)(u >> 16);
}

__device__ __forceinline__ bf16x8 cvt8(float4 x, float4 y) {
    bf16x8 r;
    r[0] = (short)f2bf(x.x); r[1] = (short)f2bf(x.y);
    r[2] = (short)f2bf(x.z); r[3] = (short)f2bf(x.w);
    r[4] = (short)f2bf(y.x); r[5] = (short)f2bf(y.y);
    r[6] = (short)f2bf(y.z); r[7] = (short)f2bf(y.w);
    return r;
}

__device__ __forceinline__ void gload16(const void* g, void* l) {
    __builtin_amdgcn_global_load_lds(
        (const __attribute__((address_space(1))) void*)g,
        (__attribute__((address_space(3))) void*)l, 16, 0, 0);
}

// ---------------- fp32 -> bf16 conversion (vectorized) ----------------
__global__ void __launch_bounds__(256) conv_bf16(const float* __restrict__ src,
                                                 unsigned short* __restrict__ dst, int n4) {
    int i = blockIdx.x * 256 + threadIdx.x;
    int st = gridDim.x * 256;
    for (; i < n4; i += st) {
        float4 v = reinterpret_cast<const float4*>(src)[i];
        ushort4 r;
        r.x = f2bf(v.x); r.y = f2bf(v.y); r.z = f2bf(v.z); r.w = f2bf(v.w);
        reinterpret_cast<ushort4*>(dst)[i] = r;
    }
}

// ---------------- router ----------------
__global__ void __launch_bounds__(256) router(const float* __restrict__ tw,
                                              const int* __restrict__ ids,
                                              int* __restrict__ tok, float* __restrict__ wgt,
                                              int* __restrict__ cnt) {
    int m = blockIdx.x * 256 + threadIdx.x;
    if (m >= MTOK) return;
#pragma unroll
    for (int t = 0; t < 2; t++) {
        int e = ids[m * 2 + t];
        int slot = atomicAdd(&cnt[e], 1);
        tok[e * CAP + slot] = m;
        wgt[e * CAP + slot] = tw[m * 2 + t];
    }
}

__global__ void scan_off(const int* __restrict__ cnt, int* __restrict__ off) {
    if (threadIdx.x == 0) {
        int s = 0;
        for (int e = 0; e < EXPERTS; e++) { off[e] = s; s += cnt[e]; }
    }
}

// ---------------- pack A: hsp[slot] = bf16(hs[tok[slot]]) ----------------
// Fuses hs conversion with router permutation so gemm1's A is SEQUENTIAL.
// 8 slots per 256-thr block (32 lanes per slot, 64 elems/lane).
__global__ void __launch_bounds__(256) pack_a(const float* __restrict__ hs,
                                              const int* __restrict__ tok,
                                              const int* __restrict__ off,
                                              unsigned short* __restrict__ hsp) {
    const int slot = blockIdx.x * 8 + (threadIdx.x >> 5);
    const int lane = threadIdx.x & 31;
    int e = 0;
#pragma unroll
    for (int k = 1; k < 8; k++) if (slot >= off[k]) e = k;
    const int idx = slot - off[e];
    const int row = tok[e * CAP + idx];
    const float* src = hs + (size_t)row * KDIM;
    unsigned short* dst = hsp + (size_t)slot * KDIM;
#pragma unroll
    for (int i = 0; i < 8; i++) {
        int c = (i * 32 + lane) * 8;
        float4 x = *(const float4*)(src + c);
        float4 y = *(const float4*)(src + c + 4);
        *(bf16x8*)(dst + c) = cvt8(x, y);
    }
}

// ====================================================================
// Ring GEMMs (128x128, BK=32, 3-slot 16KB ring, counted vmcnt(4)),
// expert->XCD pinning (bid%8==e), cb-major order (rb fastest).
// gemm1 A is now PACKED/SEQUENTIAL (hsp): co-resident rb-siblings'
// working set = 8x256KB A + 256KB B (bf16) -> L2-resident; A fetched
// into L2 once per expert. Swizzle: phys 16B slot = g ^ ((row>>1)&3),
// staged via inverse-permuted global source + matching ds_read offset.
// ====================================================================

// ---------------- GEMM1 + SiLU*up -> act (bf16) ----------------
__global__ void __launch_bounds__(256, 3) gemm1_silu(
    const unsigned short* __restrict__ hsp,
    const unsigned short* __restrict__ w1b,
    const int* __restrict__ cnt,
    const int* __restrict__ off,
    unsigned short* __restrict__ act) {
    const int bid = blockIdx.x;
    const int e = bid & 7;       // XCD pin: bid%8 -> XCD
    const int j = bid >> 3;      // 0..1407
    const int rb = j & 63;       // cb-major: rb fastest -> co-resident share B panel
    const int cb = j >> 6;       // 0..21 (22*64 = 1408 gate cols)
    const int cnt_e = cnt[e];
    if (rb * 128 >= cnt_e) return;
    const int off_e = off[e];
    const int slotA = off_e + rb * 128;   // sequential packed-A base
    const int NT = KDIM / 32;    // 64

    __shared__ __align__(16) char smem[49152];   // 3 x 16KB ring

    const int tid = threadIdx.x;
    const int w = tid >> 6, lane = tid & 63;

    // staging geometry: per-slot layout A@0(8KB), B@8192(8KB)
    const int o0 = w * 1024 + lane * 16;
    const int row0 = o0 >> 6, g0 = ((o0 >> 4) & 3) ^ ((row0 >> 1) & 3);
    const int o1 = 4096 + o0;
    const int row1 = o1 >> 6, g1 = ((o1 >> 4) & 3) ^ ((row1 >> 1) & 3);

    const int G0 = row0 >> 4, G1 = row1 >> 4;
    const size_t w1base = (size_t)e * NDIM * KDIM;
    const int wrow0 = ((G0 & 1) ? IDIM : 0) + cb * 64 + (G0 >> 1) * 16 + (row0 & 15);
    const int wrow1 = ((G1 & 1) ? IDIM : 0) + cb * 64 + (G1 >> 1) * 16 + (row1 & 15);

    const size_t srcA0 = (size_t)(slotA + row0) * KDIM + g0 * 8;
    const size_t srcA1 = (size_t)(slotA + row1) * KDIM + g1 * 8;
    const size_t srcB0 = w1base + (size_t)wrow0 * KDIM + g0 * 8;
    const size_t srcB1 = w1base + (size_t)wrow1 * KDIM + g1 * 8;

    const int wr = w >> 1, wc = w & 1;
    const int l16 = lane & 15, lg = lane >> 4;
    int aoff[4], boff[4];
#pragma unroll
    for (int m = 0; m < 4; m++) {
        int r = wr * 64 + m * 16 + l16;
        aoff[m] = r * 64 + ((lg ^ ((r >> 1) & 3)) * 16);
    }
#pragma unroll
    for (int n = 0; n < 4; n++) {
        int r = wc * 64 + n * 16 + l16;
        boff[n] = 8192 + r * 64 + ((lg ^ ((r >> 1) & 3)) * 16);
    }

    f32x4 acc[4][4];
#pragma unroll
    for (int m = 0; m < 4; m++)
#pragma unroll
        for (int n = 0; n < 4; n++) acc[m][n] = {0.f, 0.f, 0.f, 0.f};

#define STG1(t, base) { const int kof_ = (t) * 32; char* b_ = smem + (base); \
    gload16(hsp + srcA0 + kof_, b_ + w * 1024); \
    gload16(hsp + srcA1 + kof_, b_ + 4096 + w * 1024); \
    gload16(w1b + srcB0 + kof_, b_ + 8192 + w * 1024); \
    gload16(w1b + srcB1 + kof_, b_ + 12288 + w * 1024); }

    // prologue: stage tiles 0,1 into slots 0,1; wait tile 0 only
    STG1(0, 0); STG1(1, 16384);
    asm volatile("s_waitcnt vmcnt(4)" ::: "memory");
    __builtin_amdgcn_sched_barrier(0);
    __builtin_amdgcn_s_barrier();

    int sl_t = 0;        // slot byte base of tile t
    int sl_p = 32768;    // slot byte base of tile t+2

#pragma unroll 1
    for (int t = 0; t < NT; ++t) {
        if (t + 2 < NT) STG1(t + 2, sl_p);
        __builtin_amdgcn_sched_barrier(0);

        const char* db = smem + sl_t;
        bf16x8 af[4], bf[4];
#pragma unroll
        for (int m = 0; m < 4; m++) af[m] = *(const bf16x8*)(db + aoff[m]);
#pragma unroll
        for (int n = 0; n < 4; n++) bf[n] = *(const bf16x8*)(db + boff[n]);
        __builtin_amdgcn_s_setprio(1);
#pragma unroll
        for (int m = 0; m < 4; m++)
#pragma unroll
            for (int n = 0; n < 4; n++)
                acc[m][n] = __builtin_amdgcn_mfma_f32_16x16x32_bf16(af[m], bf[n], acc[m][n], 0, 0, 0);
        __builtin_amdgcn_s_setprio(0);
        __builtin_amdgcn_sched_barrier(0);
        if (t + 2 < NT)      { asm volatile("s_waitcnt vmcnt(4)" ::: "memory"); }
        else if (t + 1 < NT) { asm volatile("s_waitcnt vmcnt(0)" ::: "memory"); }
        __builtin_amdgcn_sched_barrier(0);
        __builtin_amdgcn_s_barrier();

        sl_t += 16384; if (sl_t == 49152) sl_t = 0;
        sl_p += 16384; if (sl_p == 49152) sl_p = 0;
    }
#undef STG1

    // epilogue: n even = gate frag, n+1 = up frag (same 16 cols)
#pragma unroll
    for (int m = 0; m < 4; m++) {
#pragma unroll
        for (int np = 0; np < 2; np++) {
            f32x4 g4 = acc[m][np * 2];
            f32x4 u4 = acc[m][np * 2 + 1];
            int icol = cb * 64 + (wc * 2 + np) * 16 + l16;
#pragma unroll
            for (int j2 = 0; j2 < 4; j2++) {
                int grow = rb * 128 + wr * 64 + m * 16 + lg * 4 + j2;
                if (grow < cnt_e) {
                    float gt = g4[j2], up = u4[j2];
                    float s = gt / (1.f + __expf(-gt));
                    act[(size_t)(off_e + grow) * IDIM + icol] = f2bf(s * up);
                }
            }
        }
    }
}

// ---------------- GEMM2 + weighted scatter ----------------
__global__ void __launch_bounds__(256, 3) gemm2_scatter(
    const unsigned short* __restrict__ act,
    const unsigned short* __restrict__ w2b,
    const int* __restrict__ tok,
    const float* __restrict__ wgt,
    const int* __restrict__ cnt,
    const int* __restrict__ off,
    float* __restrict__ out) {
    const int bid = blockIdx.x;
    const int e = bid & 7;       // XCD pin
    const int j = bid >> 3;      // 0..1023
    const int rb = j & 63;       // cb-major: rb fastest
    const int cb = j >> 6;       // 0..15 (16*128 = 2048 out cols)
    const int cnt_e = cnt[e];
    if (rb * 128 >= cnt_e) return;
    const int off_e = off[e];
    const int NT = IDIM / 32;    // 44

    __shared__ __align__(16) char smem[49152];
    __shared__ int toks[128];
    __shared__ float wgts[128];

    const int tid = threadIdx.x;
    const int w = tid >> 6, lane = tid & 63;
    if (tid < 128) {
        int slot = rb * 128 + tid;
        bool v = slot < cnt_e;
        toks[tid] = v ? tok[e * CAP + slot] : 0;
        wgts[tid] = v ? wgt[e * CAP + slot] : 0.f;
    }
    __syncthreads();

    const int o0 = w * 1024 + lane * 16;
    const int row0 = o0 >> 6, g0 = ((o0 >> 4) & 3) ^ ((row0 >> 1) & 3);
    const int o1 = 4096 + o0;
    const int row1 = o1 >> 6, g1 = ((o1 >> 4) & 3) ^ ((row1 >> 1) & 3);

    const int s0 = rb * 128 + row0, s1 = rb * 128 + row1;
    const size_t pa0 = (size_t)(off_e + (s0 < cnt_e ? s0 : 0)) * IDIM + g0 * 8;
    const size_t pa1 = (size_t)(off_e + (s1 < cnt_e ? s1 : 0)) * IDIM + g1 * 8;
    const size_t w2base = (size_t)e * KDIM * IDIM;
    const size_t pb0 = w2base + (size_t)(cb * 128 + row0) * IDIM + g0 * 8;
    const size_t pb1 = w2base + (size_t)(cb * 128 + row1) * IDIM + g1 * 8;

    const int wr = w >> 1, wc = w & 1;
    const int l16 = lane & 15, lg = lane >> 4;
    int aoff[4], boff[4];
#pragma unroll
    for (int m = 0; m < 4; m++) {
        int r = wr * 64 + m * 16 + l16;
        aoff[m] = r * 64 + ((lg ^ ((r >> 1) & 3)) * 16);
    }
#pragma unroll
    for (int n = 0; n < 4; n++) {
        int r = wc * 64 + n * 16 + l16;
        boff[n] = 8192 + r * 64 + ((lg ^ ((r >> 1) & 3)) * 16);
    }

    f32x4 acc[4][4];
#pragma unroll
    for (int m = 0; m < 4; m++)
#pragma unroll
        for (int n = 0; n < 4; n++) acc[m][n] = {0.f, 0.f, 0.f, 0.f};

#define STG2(t, base) { const int kof_ = (t) * 32; char* b_ = smem + (base); \
    gload16(act + pa0 + kof_, b_ + w * 1024); \
    gload16(act + pa1 + kof_, b_ + 4096 + w * 1024); \
    gload16(w2b + pb0 + kof_, b_ + 8192 + w * 1024); \
    gload16(w2b + pb1 + kof_, b_ + 12288 + w * 1024); }

    STG2(0, 0); STG2(1, 16384);
    asm volatile("s_waitcnt vmcnt(4)" ::: "memory");
    __builtin_amdgcn_sched_barrier(0);
    __builtin_amdgcn_s_barrier();

    int sl_t = 0;
    int sl_p = 32768;

#pragma unroll 1
    for (int t = 0; t < NT; ++t) {
        if (t + 2 < NT) STG2(t + 2, sl_p);
        __builtin_amdgcn_sched_barrier(0);

        const char* db = smem + sl_t;
        bf16x8 af[4], bf[4];
#pragma unroll
        for (int m = 0; m < 4; m++) af[m] = *(const bf16x8*)(db + aoff[m]);
#pragma unroll
        for (int n = 0; n < 4; n++) bf[n] = *(const bf16x8*)(db + boff[n]);
        __builtin_amdgcn_s_setprio(1);
#pragma unroll
        for (int m = 0; m < 4; m++)
#pragma unroll
            for (int n = 0; n < 4; n++)
                acc[m][n] = __builtin_amdgcn_mfma_f32_16x16x32_bf16(af[m], bf[n], acc[m][n], 0, 0, 0);
        __builtin_amdgcn_s_setprio(0);
        __builtin_amdgcn_sched_barrier(0);
        if (t + 2 < NT)      { asm volatile("s_waitcnt vmcnt(4)" ::: "memory"); }
        else if (t + 1 < NT) { asm volatile("s_waitcnt vmcnt(0)" ::: "memory"); }
        __builtin_amdgcn_sched_barrier(0);
        __builtin_amdgcn_s_barrier();

        sl_t += 16384; if (sl_t == 49152) sl_t = 0;
        sl_p += 16384; if (sl_p == 49152) sl_p = 0;
    }
#undef STG2

    // scatter: out[token, k] += weight * y  (TOPK=2, fp32 atomic add, commutative)
#pragma unroll
    for (int m = 0; m < 4; m++) {
#pragma unroll
        for (int n = 0; n < 4; n++) {
            int kcol = cb * 128 + wc * 64 + n * 16 + l16;
#pragma unroll
            for (int j2 = 0; j2 < 4; j2++) {
                int lrow = wr * 64 + m * 16 + lg * 4 + j2;
                if (rb * 128 + lrow < cnt_e) {
                    atomicAdd(&out[(size_t)toks[lrow] * KDIM + kcol],
                              wgts[lrow] * acc[m][n][j2]);
                }
            }
        }
    }
}

extern "C" void kernel_launch(void* const* d_in, const int* in_sizes, int n_in,
                              void* d_out, int out_size, void* d_ws, size_t ws_size,
                              hipStream_t stream) {
    const float* hs  = (const float*)d_in[0];
    const float* w1  = (const float*)d_in[1];
    const float* w2  = (const float*)d_in[2];
    const float* tw  = (const float*)d_in[3];
    const int*   ids = (const int*)d_in[4];
    float* out = (float*)d_out;

    // ws layout: hsp time-shares the w2b region (conv_w2 runs AFTER gemm1)
    char* ws = (char*)d_ws;
    unsigned short* w1b  = (unsigned short*)(ws);                  //  92,274,688
    unsigned short* hsp  = (unsigned short*)(ws + 92274688ull);    //  34,078,720 (8320 rows, padded)
    unsigned short* w2b  = (unsigned short*)(ws + 92274688ull);    //  46,137,344 (after gemm1)
    unsigned short* actb = (unsigned short*)(ws + 138412032ull);   //  23,068,672
    int*   tokb = (int*)  (ws + 161480704ull);                     //     262,144
    float* wgtb = (float*)(ws + 161742848ull);                     //     262,144
    int*   cntb = (int*)  (ws + 162004992ull);                     //          64
    int*   offb = (int*)  (ws + 162005056ull);                     //          32

    hipMemsetAsync(d_out, 0, (size_t)MTOK * KDIM * sizeof(float), stream);
    hipMemsetAsync(cntb, 0, 64, stream);

    conv_bf16<<<4096, 256, 0, stream>>>(w1, w1b, EXPERTS * NDIM * KDIM / 4);

    router<<<MTOK / 256, 256, 0, stream>>>(tw, ids, tokb, wgtb, cntb);
    scan_off<<<1, 64, 0, stream>>>(cntb, offb);
    pack_a<<<MTOK * 2 / 8, 256, 0, stream>>>(hs, tokb, offb, hsp);

    // linear grids with bid%8 == expert (XCD pinning), cb-major order
    gemm1_silu<<<dim3(22 * 64 * 8, 1, 1), 256, 0, stream>>>(hsp, w1b, cntb, offb, actb);

    // conv_w2 AFTER gemm1 (w2b overwrites hsp region; stream-ordered)
    conv_bf16<<<2048, 256, 0, stream>>>(w2, w2b, EXPERTS * KDIM * IDIM / 4);

    gemm2_scatter<<<dim3(16 * 64 * 8, 1, 1), 256, 0, stream>>>(actb, w2b, tokb, wgtb, cntb, offb, out);
}